// Round 5
// baseline (91.230 us; speedup 1.0000x reference)
//
#include <hip/hip_runtime.h>
#include <hip/hip_bf16.h>

#ifndef __has_builtin
#define __has_builtin(x) 0
#endif

typedef __attribute__((ext_vector_type(8))) short short8;   // 8 bf16 = 4 VGPRs
typedef __attribute__((ext_vector_type(4))) float floatx4;  // MFMA C/D

__device__ __forceinline__ float fast_exp2(float x) {
#if __has_builtin(__builtin_amdgcn_exp2f)
    return __builtin_amdgcn_exp2f(x);
#else
    return exp2f(x);
#endif
}
__device__ __forceinline__ float fast_rcp(float x) {
#if __has_builtin(__builtin_amdgcn_rcpf)
    return __builtin_amdgcn_rcpf(x);
#else
    return 1.0f / x;
#endif
}
__device__ __forceinline__ unsigned pack_bf16(float a, float b) {
    __hip_bfloat162 h = __float22bfloat162_rn(make_float2(a, b));  // rn both
    union { __hip_bfloat162 h2; unsigned u; } cv;
    cv.h2 = h;
    return cv.u;      // low half = a (k even), high = b (k odd)
}

#define VQ_K 256
#define BLK  256
#define T    8       // 16-row m-tiles per wave -> 128 m's/wave, 4096 waves

// MFMA-offload design. Lane (q=lane>>4, ml=lane&15) computes softmax weights
// p = exp2(x.c2 + b) directly in 16x16x32 bf16 A-fragment layout
// (m = ml, k = q*8 + j), so the PV GEMM O = P.[C|1] runs on the MFMA pipe
// with zero layout conversion. bf16 P has fp32 exponent range -> unnormalized
// weights need no row-max pass. Dot stays fp32 VALU (full precision).
// Per wave-(m,k) unit: 4 fma + 0.5 cvt_pk (main, ~9cy) + 1 v_exp (trans ~16cy).
__global__ __launch_bounds__(BLK) void vq_mfma(const float* __restrict__ x,
                                               const float* __restrict__ center,
                                               float* __restrict__ out) {
    // c2 rows staggered: off(k) = k*8 + ((k>>3)&3)*4 so the 4 quarter-uniform
    // addresses per ds_read_b128 land on disjoint bank quads.
    __shared__ float    s_c2[2056];
    __shared__ float    s_b[VQ_K];
    __shared__ unsigned s_v[8 * 64 * 4];   // prepacked V frags [chunk][lane][4]

    // ---- init: c2 / bias, one k per thread ----
    {
        const float L2E = 1.4426950408889634f;
        int k = threadIdx.x;
        float4 c = reinterpret_cast<const float4*>(center)[k];
        float b = -L2E * (c.x * c.x + c.y * c.y + c.z * c.z + c.w * c.w);
        int off = k * 8 + ((k >> 3) & 3) * 4;
        float s = 2.0f * L2E;
        s_c2[off + 0] = s * c.x;
        s_c2[off + 1] = s * c.y;
        s_c2[off + 2] = s * c.z;
        s_c2[off + 3] = s * c.w;
        s_b[k] = b;
    }
    // ---- init: V fragments. V[k][n] = c_k[n] (n<4), 1 (n==4), 0 else.
    // B-frag layout mirrors A: n = lane&15, k = (lane>>4)*8 + j.
    for (int f = threadIdx.x; f < 512; f += BLK) {   // 8 chunks x 64 lanes
        int chunk = f >> 6, ln = f & 63;
        int n = ln & 15, q = ln >> 4;
#pragma unroll
        for (int r = 0; r < 4; ++r) {
            int k0 = chunk * 32 + q * 8 + 2 * r;
            float v0 = (n < 4) ? center[k0 * 4 + n]       : (n == 4 ? 1.f : 0.f);
            float v1 = (n < 4) ? center[(k0 + 1) * 4 + n] : (n == 4 ? 1.f : 0.f);
            s_v[f * 4 + r] = pack_bf16(v0, v1);
        }
    }
    __syncthreads();

    const int lane = threadIdx.x & 63;
    const int wv   = threadIdx.x >> 6;
    const int q    = lane >> 4;
    const int ml   = lane & 15;

    const int mbase = blockIdx.x * (4 * 16 * T) + wv * (16 * T);
    const float4* __restrict__ x4 = reinterpret_cast<const float4*>(x);

    // x row for each of this lane's T tiles (4 quarters read same addr -> L1)
    float4 xr[T];
#pragma unroll
    for (int t = 0; t < T; ++t) xr[t] = x4[mbase + t * 16 + ml];

    floatx4 O[T];
#pragma unroll
    for (int t = 0; t < T; ++t) O[t] = (floatx4){0.f, 0.f, 0.f, 0.f};

    union AFrag { unsigned u[4]; short8 v; };

    for (int chunk = 0; chunk < 8; ++chunk) {
        AFrag areg[T];
#pragma unroll
        for (int jj = 0; jj < 4; ++jj) {
            int k0 = chunk * 32 + q * 8 + 2 * jj;
            int o0 = k0 * 8 + q * 4;               // stagger: (k0>>3)&3 == q
            float4 c2a = *reinterpret_cast<const float4*>(s_c2 + o0);
            float4 c2b = *reinterpret_cast<const float4*>(s_c2 + o0 + 8);
            float  ba  = s_b[k0];
            float  bb  = s_b[k0 + 1];
#pragma unroll
            for (int t = 0; t < T; ++t) {
                float s0 = fmaf(xr[t].x, c2a.x, ba);
                s0 = fmaf(xr[t].y, c2a.y, s0);
                s0 = fmaf(xr[t].z, c2a.z, s0);
                s0 = fmaf(xr[t].w, c2a.w, s0);
                float s1 = fmaf(xr[t].x, c2b.x, bb);
                s1 = fmaf(xr[t].y, c2b.y, s1);
                s1 = fmaf(xr[t].z, c2b.z, s1);
                s1 = fmaf(xr[t].w, c2b.w, s1);
                areg[t].u[jj] = pack_bf16(fast_exp2(s0), fast_exp2(s1));
            }
        }
        short8 bfrag = reinterpret_cast<const short8*>(s_v)[chunk * 64 + lane];
#pragma unroll
        for (int t = 0; t < T; ++t) {
            O[t] = __builtin_amdgcn_mfma_f32_16x16x32_bf16(areg[t].v, bfrag,
                                                           O[t], 0, 0, 0);
        }
    }

    // ---- epilogue: D layout col n = lane&15, rows m = q*4 + reg.
    // col 4 holds den = sum(p); broadcast it to cols 0..3 via bpermute.
#pragma unroll
    for (int t = 0; t < T; ++t) {
#pragma unroll
        for (int r = 0; r < 4; ++r) {
            float den = __shfl(O[t][r], (lane & 48) + 4, 64);
            float val = O[t][r] * fast_rcp(den);
            int m = mbase + t * 16 + q * 4 + r;
            if (ml < 4) out[m * 4 + ml] = val;
        }
    }
}

extern "C" void kernel_launch(void* const* d_in, const int* in_sizes, int n_in,
                              void* d_out, int out_size, void* d_ws, size_t ws_size,
                              hipStream_t stream) {
    const float* x      = (const float*)d_in[0];   // [8, 262144] fp32
    const float* center = (const float*)d_in[1];   // [256, 4] fp32
    float* out = (float*)d_out;

    int nvec   = in_sizes[0] / 4;                  // 524288 m-vectors
    int blocks = nvec / (4 * 16 * T);              // 1024
    vq_mfma<<<blocks, BLK, 0, stream>>>(x, center, out);
}